// Round 1
// baseline (513.122 us; speedup 1.0000x reference)
//
#include <hip/hip_runtime.h>

// DenseGrid trilinear interpolation, MI355X.
// Layout: 9 threads per point; thread f in [0,9) owns feature pair (2f, 2f+1).
// Codebook row = 18 floats = 72 B (8-aligned for every row index) -> float2 loads.
// A 64-lane wave's corner-gather covers ~7 points x 72 B contiguous each:
// ~10-16 cacheline requests/instr vs 64 for the one-thread-per-point layout.

constexpr int RES = 128;
constexpr int TPB = 576;        // 9 waves; 64 points per block
constexpr int PPB = TPB / 9;    // 64 points per block

__global__ __launch_bounds__(TPB)
void dense_grid_trilerp(const float* __restrict__ pts,
                        const float* __restrict__ cb,
                        const float* __restrict__ tr,
                        float* __restrict__ out,
                        int npts)
{
    // Stage this block's 64 points (192 floats) coalesced into LDS.
    __shared__ float spts[PPB * 3];
    if (threadIdx.x < PPB * 3) {
        int g = blockIdx.x * (PPB * 3) + threadIdx.x;
        spts[threadIdx.x] = (g < npts * 3) ? pts[g] : 0.0f;
    }
    __syncthreads();

    const int pl = threadIdx.x / 9;        // local point index
    const int f  = threadIdx.x - pl * 9;   // feature pair 0..8
    const int p  = blockIdx.x * PPB + pl;
    if (p >= npts) return;

    // ---- q = inv(R) * (x - t); all operands wave-uniform (identity at runtime,
    // but implemented generally per the reference). 3x3 inverse via adjugate.
    const float a = tr[0], b = tr[1],  c = tr[2],  tx = tr[3];
    const float d = tr[4], e = tr[5],  g_ = tr[6], ty = tr[7];
    const float h = tr[8], i_ = tr[9], j = tr[10], tz = tr[11];
    const float det = a*(e*j - g_*i_) - b*(d*j - g_*h) + c*(d*i_ - e*h);
    const float rd  = 1.0f / det;
    const float m00 = (e*j - g_*i_) * rd, m01 = (c*i_ - b*j) * rd, m02 = (b*g_ - c*e) * rd;
    const float m10 = (g_*h - d*j) * rd,  m11 = (a*j - c*h) * rd,  m12 = (c*d - a*g_) * rd;
    const float m20 = (d*i_ - e*h) * rd,  m21 = (b*h - a*i_) * rd, m22 = (a*e - b*d) * rd;

    const float x = spts[pl*3 + 0] - tx;
    const float y = spts[pl*3 + 1] - ty;
    const float z = spts[pl*3 + 2] - tz;
    const float qx = (m00*x + m01*y + m02*z) * (float)(RES - 1);
    const float qy = (m10*x + m11*y + m12*z) * (float)(RES - 1);
    const float qz = (m20*x + m21*y + m22*z) * (float)(RES - 1);

    // Reference semantics: w = p - floor(p) (unclamped); indices clamped.
    const float fx = floorf(qx), fy = floorf(qy), fz = floorf(qz);
    const float wx1 = qx - fx, wy1 = qy - fy, wz1 = qz - fz;
    const float wx0 = 1.0f - wx1, wy0 = 1.0f - wy1, wz0 = 1.0f - wz1;
    const int ix0 = min(max((int)fx, 0), RES - 1); const int ix1 = min(ix0 + 1, RES - 1);
    const int iy0 = min(max((int)fy, 0), RES - 1); const int iy1 = min(iy0 + 1, RES - 1);
    const int iz0 = min(max((int)fz, 0), RES - 1); const int iz1 = min(iz0 + 1, RES - 1);

    int   ro[8];   // corner row indices
    float w[8];    // corner weights
    #pragma unroll
    for (int k = 0; k < 8; ++k) {
        const int dx = k & 1, dy = (k >> 1) & 1, dz = k >> 2;
        const int ix = dx ? ix1 : ix0;
        const int iy = dy ? iy1 : iy0;
        const int iz = dz ? iz1 : iz0;
        ro[k] = ix + (iy << 7) + (iz << 14);
        w[k]  = (dx ? wx1 : wx0) * (dy ? wy1 : wy0) * (dz ? wz1 : wz0);
    }

    // Issue all 8 gathers first (ILP), then accumulate.
    const float* cbf = cb + 2 * f;            // this thread's feature-pair column
    float2 v[8];
    #pragma unroll
    for (int k = 0; k < 8; ++k)
        v[k] = *reinterpret_cast<const float2*>(cbf + ro[k] * 18);

    float ax = 0.0f, ay = 0.0f;
    #pragma unroll
    for (int k = 0; k < 8; ++k) { ax += v[k].x * w[k]; ay += v[k].y * w[k]; }

    // Coalesced: 9 consecutive threads write 9 consecutive float2 of one row.
    *reinterpret_cast<float2*>(out + p * 18 + 2 * f) = make_float2(ax, ay);
}

extern "C" void kernel_launch(void* const* d_in, const int* in_sizes, int n_in,
                              void* d_out, int out_size, void* d_ws, size_t ws_size,
                              hipStream_t stream) {
    const float* pts = (const float*)d_in[0];   // [4*524288, 3] f32
    const float* cb  = (const float*)d_in[1];   // [128^3, 18] f32
    const float* tr  = (const float*)d_in[2];   // [4,4] f32
    float* out = (float*)d_out;                 // [4*524288, 18] f32

    const int npts   = in_sizes[0] / 3;
    const int blocks = (npts + PPB - 1) / PPB;
    dense_grid_trilerp<<<blocks, TPB, 0, stream>>>(pts, cb, tr, out, npts);
}

// Round 3
// 511.009 us; speedup vs baseline: 1.0041x; 1.0041x over previous
//
#include <hip/hip_runtime.h>

// DenseGrid trilinear interpolation, MI355X.
// R2: same as R1 (non-temporal output/pts streams so they stop evicting the
// 151 MB codebook from the 256 MB Infinity Cache), with the compile fix:
// __builtin_nontemporal_* requires a clang ext_vector_type, not HIP float2.
//
// Layout: 9 threads per point; thread f in [0,9) owns feature pair (2f, 2f+1).
// Codebook row = 18 floats = 72 B (8-aligned for every row) -> float2 loads.

constexpr int RES = 128;
constexpr int TPB = 576;        // 9 waves; 64 points per block
constexpr int PPB = TPB / 9;    // 64 points per block

typedef float vf2 __attribute__((ext_vector_type(2)));

__global__ __launch_bounds__(TPB)
void dense_grid_trilerp(const float* __restrict__ pts,
                        const float* __restrict__ cb,
                        const float* __restrict__ tr,
                        float* __restrict__ out,
                        int npts)
{
    // Stage this block's 64 points (192 floats) coalesced into LDS.
    __shared__ float spts[PPB * 3];
    if (threadIdx.x < PPB * 3) {
        int g = blockIdx.x * (PPB * 3) + threadIdx.x;
        spts[threadIdx.x] = (g < npts * 3) ? __builtin_nontemporal_load(&pts[g]) : 0.0f;
    }
    __syncthreads();

    const int pl = threadIdx.x / 9;        // local point index
    const int f  = threadIdx.x - pl * 9;   // feature pair 0..8
    const int p  = blockIdx.x * PPB + pl;
    if (p >= npts) return;

    // ---- q = inv(R) * (x - t); wave-uniform operands (identity at runtime,
    // but implemented generally per the reference). 3x3 inverse via adjugate.
    const float a = tr[0], b = tr[1],  c = tr[2],  tx = tr[3];
    const float d = tr[4], e = tr[5],  g_ = tr[6], ty = tr[7];
    const float h = tr[8], i_ = tr[9], j = tr[10], tz = tr[11];
    const float det = a*(e*j - g_*i_) - b*(d*j - g_*h) + c*(d*i_ - e*h);
    const float rd  = 1.0f / det;
    const float m00 = (e*j - g_*i_) * rd, m01 = (c*i_ - b*j) * rd, m02 = (b*g_ - c*e) * rd;
    const float m10 = (g_*h - d*j) * rd,  m11 = (a*j - c*h) * rd,  m12 = (c*d - a*g_) * rd;
    const float m20 = (d*i_ - e*h) * rd,  m21 = (b*h - a*i_) * rd, m22 = (a*e - b*d) * rd;

    const float x = spts[pl*3 + 0] - tx;
    const float y = spts[pl*3 + 1] - ty;
    const float z = spts[pl*3 + 2] - tz;
    const float qx = (m00*x + m01*y + m02*z) * (float)(RES - 1);
    const float qy = (m10*x + m11*y + m12*z) * (float)(RES - 1);
    const float qz = (m20*x + m21*y + m22*z) * (float)(RES - 1);

    // Reference semantics: w = p - floor(p) (unclamped); indices clamped.
    const float fx = floorf(qx), fy = floorf(qy), fz = floorf(qz);
    const float wx1 = qx - fx, wy1 = qy - fy, wz1 = qz - fz;
    const float wx0 = 1.0f - wx1, wy0 = 1.0f - wy1, wz0 = 1.0f - wz1;
    const int ix0 = min(max((int)fx, 0), RES - 1); const int ix1 = min(ix0 + 1, RES - 1);
    const int iy0 = min(max((int)fy, 0), RES - 1); const int iy1 = min(iy0 + 1, RES - 1);
    const int iz0 = min(max((int)fz, 0), RES - 1); const int iz1 = min(iz0 + 1, RES - 1);

    int   ro[8];   // corner row indices
    float w[8];    // corner weights
    #pragma unroll
    for (int k = 0; k < 8; ++k) {
        const int dx = k & 1, dy = (k >> 1) & 1, dz = k >> 2;
        const int ix = dx ? ix1 : ix0;
        const int iy = dy ? iy1 : iy0;
        const int iz = dz ? iz1 : iz0;
        ro[k] = ix + (iy << 7) + (iz << 14);
        w[k]  = (dx ? wx1 : wx0) * (dy ? wy1 : wy0) * (dz ? wz1 : wz0);
    }

    // Issue all 8 gathers first (ILP), then accumulate. These MUST stay
    // cacheable (codebook reuse is the whole game) — no nt here.
    const float* cbf = cb + 2 * f;            // this thread's feature-pair column
    vf2 v[8];
    #pragma unroll
    for (int k = 0; k < 8; ++k)
        v[k] = *reinterpret_cast<const vf2*>(cbf + ro[k] * 18);

    float ax = 0.0f, ay = 0.0f;
    #pragma unroll
    for (int k = 0; k < 8; ++k) { ax += v[k].x * w[k]; ay += v[k].y * w[k]; }

    // Coalesced (block writes one contiguous 4.6 KB span) + non-temporal:
    // keep the output stream out of L3 so the codebook stays resident.
    vf2 r; r.x = ax; r.y = ay;
    __builtin_nontemporal_store(r, reinterpret_cast<vf2*>(out + p * 18 + 2 * f));
}

extern "C" void kernel_launch(void* const* d_in, const int* in_sizes, int n_in,
                              void* d_out, int out_size, void* d_ws, size_t ws_size,
                              hipStream_t stream) {
    const float* pts = (const float*)d_in[0];   // [4*524288, 3] f32
    const float* cb  = (const float*)d_in[1];   // [128^3, 18] f32
    const float* tr  = (const float*)d_in[2];   // [4,4] f32
    float* out = (float*)d_out;                 // [4*524288, 18] f32

    const int npts   = in_sizes[0] / 3;
    const int blocks = (npts + PPB - 1) / PPB;
    dense_grid_trilerp<<<blocks, TPB, 0, stream>>>(pts, cb, tr, out, npts);
}